// Round 1
// baseline (287.534 us; speedup 1.0000x reference)
//
#include <hip/hip_runtime.h>
#include <cstdint>
#include <cstddef>

typedef _Float16 f16;
typedef __attribute__((ext_vector_type(4))) _Float16 f16x4;
typedef __attribute__((ext_vector_type(8))) _Float16 f16x8;
typedef __attribute__((ext_vector_type(4))) float f32x4;

static constexpr int BB = 4;
static constexpr int SS = 2048;
static constexpr int EE = 1024;

static constexpr int BM = 128, BN = 128, BK = 32;

// async global->LDS, 16B per lane. LDS dest must be wave-uniform base + lane*16.
__device__ __forceinline__ void gload_lds16(const f16* g, f16* l) {
  __builtin_amdgcn_global_load_lds(
      (const __attribute__((address_space(1))) void*)g,
      (__attribute__((address_space(3))) void*)l, 16, 0, 0);
}

struct Frag {
  int lane, wave, wy, wx, l16, quad;
  __device__ Frag() {
    const int tid = threadIdx.x;
    lane = tid & 63; wave = tid >> 6;
    wy = wave >> 1; wx = wave & 1;
    l16 = lane & 15; quad = lane >> 4;
  }
};

// C[m,n] = sum_k A[m,k] * Bt[n,k]   (both row-major, contraction over fast dim)
// 128x128 tile, 256 threads (4 waves, 2x2 wave grid, 4x4 16x16 MFMA frags/wave)
__device__ __forceinline__ void gemm_core(
    const f16* __restrict__ A, const f16* __restrict__ Bt,
    int lda, int ldb, int kTiles,
    f16* __restrict__ Ash, f16* __restrict__ Bsh,
    f32x4 acc[4][4], const Frag& fr)
{
  // staging: 128x32 f16 tile = 8KB = 512 chunks of 16B; 2 chunks/thread per matrix
  const int ca0 = fr.wave * 128 + fr.lane;   // chunk id in [0,512)
  const int ca1 = ca0 + 64;
  const int ra0 = ca0 >> 2, ka0 = (ca0 & 3) << 3;  // row in tile, col (f16 elems)
  const int ra1 = ca1 >> 2, ka1 = (ca1 & 3) << 3;

  const f16* gA0 = A + (size_t)ra0 * lda + ka0;
  const f16* gA1 = A + (size_t)ra1 * lda + ka1;
  const f16* gB0 = Bt + (size_t)ra0 * ldb + ka0;
  const f16* gB1 = Bt + (size_t)ra1 * ldb + ka1;
  f16* lA0 = Ash + ca0 * 8;   // = wave-uniform base (wave*2048B [+1024B]) + lane*16B
  f16* lA1 = Ash + ca1 * 8;
  f16* lB0 = Bsh + ca0 * 8;
  f16* lB1 = Bsh + ca1 * 8;

  for (int kt = 0; kt < kTiles; ++kt) {
    const int ko = kt * BK;
    gload_lds16(gA0 + ko, lA0);
    gload_lds16(gA1 + ko, lA1);
    gload_lds16(gB0 + ko, lB0);
    gload_lds16(gB1 + ko, lB1);
    __syncthreads();   // drains vmcnt(0) before barrier -> LDS tiles ready
    f16x8 af[4], bf[4];
#pragma unroll
    for (int mi = 0; mi < 4; ++mi)
      af[mi] = *(const f16x8*)(Ash + (fr.wy * 64 + mi * 16 + fr.l16) * BK + fr.quad * 8);
#pragma unroll
    for (int ni = 0; ni < 4; ++ni)
      bf[ni] = *(const f16x8*)(Bsh + (fr.wx * 64 + ni * 16 + fr.l16) * BK + fr.quad * 8);
#pragma unroll
    for (int mi = 0; mi < 4; ++mi)
#pragma unroll
      for (int ni = 0; ni < 4; ++ni)
        acc[mi][ni] = __builtin_amdgcn_mfma_f32_16x16x32_f16(af[mi], bf[ni], acc[mi][ni], 0, 0, 0);
    __syncthreads();
  }
}

// ---------------- cast fp32 -> f16 ----------------
__global__ __launch_bounds__(256) void cast_kernel(
    const float* __restrict__ in, f16* __restrict__ out, int n4)
{
  const int i = blockIdx.x * 256 + threadIdx.x;
  if (i < n4) {
    const float4 f = ((const float4*)in)[i];
    f16x4 h;
    h.x = (f16)f.x; h.y = (f16)f.y; h.z = (f16)f.z; h.w = (f16)f.w;
    ((f16x4*)out)[i] = h;
  }
}

// ---------------- QKV projection: C = X @ W^T + b ----------------
__global__ __launch_bounds__(256, 2) void qkv_kernel(
    const f16* __restrict__ X,
    const f16* __restrict__ W0, const f16* __restrict__ W1, const f16* __restrict__ W2,
    const float* __restrict__ b0, const float* __restrict__ b1, const float* __restrict__ b2,
    f16* __restrict__ O0, f16* __restrict__ O1, f16* __restrict__ O2)
{
  __shared__ __align__(16) f16 Ash[BM * BK];
  __shared__ __align__(16) f16 Bsh[BN * BK];
  const int z = blockIdx.z;
  const f16* W = (z == 0) ? W0 : (z == 1) ? W1 : W2;
  const float* bias = (z == 0) ? b0 : (z == 1) ? b1 : b2;
  f16* out = (z == 0) ? O0 : (z == 1) ? O1 : O2;
  const int row0 = blockIdx.x * BM, col0 = blockIdx.y * BN;
  Frag fr;
  f32x4 acc[4][4] = {};
  gemm_core(X + (size_t)row0 * EE, W + (size_t)col0 * EE, EE, EE, EE / BK, Ash, Bsh, acc, fr);
#pragma unroll
  for (int ni = 0; ni < 4; ++ni) {
    const int c = col0 + fr.wx * 64 + ni * 16 + fr.l16;
    const float bv = bias[c];
#pragma unroll
    for (int mi = 0; mi < 4; ++mi) {
      const int r = row0 + fr.wy * 64 + mi * 16 + fr.quad * 4;
#pragma unroll
      for (int i = 0; i < 4; ++i)
        out[(size_t)(r + i) * EE + c] = (f16)(acc[mi][ni][i] + bv);
    }
  }
}

// ---------------- V transpose: Vt[e][s] = V[s][e] (per batch) ----------------
__global__ __launch_bounds__(256) void transpose_kernel(
    const f16* __restrict__ V, f16* __restrict__ Vt)
{
  __shared__ __align__(16) f16 t[64][68];
  const int b = blockIdx.z;
  const int s0 = blockIdx.x * 64, e0 = blockIdx.y * 64;
  const int tid = threadIdx.x;
  const int r = tid >> 4;
  const int c4 = (tid & 15) << 2;
  const f16* src = V + (size_t)b * SS * EE;
  f16* dst = Vt + (size_t)b * EE * SS;
#pragma unroll
  for (int i = 0; i < 4; ++i) {
    const int row = i * 16 + r;
    const f16x4 v = *(const f16x4*)(src + (size_t)(s0 + row) * EE + e0 + c4);
    *(f16x4*)&t[row][c4] = v;
  }
  __syncthreads();
#pragma unroll
  for (int i = 0; i < 4; ++i) {
    const int row = i * 16 + r;   // e-local
    f16x4 v;
    v.x = t[c4 + 0][row]; v.y = t[c4 + 1][row];
    v.z = t[c4 + 2][row]; v.w = t[c4 + 3][row];
    *(f16x4*)(dst + (size_t)(e0 + row) * SS + s0 + c4) = v;
  }
}

// ---------------- scores: Sc[q,k] = (Q[q,:] . K[k,:]) / 32, lower-tri tiles only ----------------
__global__ __launch_bounds__(256, 2) void scores_kernel(
    const f16* __restrict__ Q, const f16* __restrict__ Kh, f16* __restrict__ Sc)
{
  __shared__ __align__(16) f16 Ash[BM * BK];
  __shared__ __align__(16) f16 Bsh[BN * BK];
  const int qt = blockIdx.x, kt = blockIdx.y, b = blockIdx.z;
  if (kt > qt) return;   // causal: tiles fully above diagonal never needed
  const f16* A  = Q  + (size_t)b * SS * EE + (size_t)qt * BM * EE;
  const f16* Bp = Kh + (size_t)b * SS * EE + (size_t)kt * BN * EE;
  f16* out = Sc + (size_t)b * SS * SS;
  Frag fr;
  f32x4 acc[4][4] = {};
  gemm_core(A, Bp, EE, EE, EE / BK, Ash, Bsh, acc, fr);
  const float scale = 0.03125f;   // 1/sqrt(1024)
#pragma unroll
  for (int ni = 0; ni < 4; ++ni) {
    const int c = kt * BN + fr.wx * 64 + ni * 16 + fr.l16;
#pragma unroll
    for (int mi = 0; mi < 4; ++mi) {
      const int r = qt * BM + fr.wy * 64 + mi * 16 + fr.quad * 4;
#pragma unroll
      for (int i = 0; i < 4; ++i)
        out[(size_t)(r + i) * SS + c] = (f16)(acc[mi][ni][i] * scale);
    }
  }
}

// ---------------- in-place causal softmax over row q (reads k<=q, zero-fills to tile edge) ----------------
__global__ __launch_bounds__(256) void softmax_kernel(f16* __restrict__ Sc)
{
  const int q = blockIdx.x, b = blockIdx.y;
  f16* row = Sc + (size_t)b * SS * SS + (size_t)q * SS;
  const int n = q + 1;
  const int tid = threadIdx.x;
  float v[8];
  float m = -1e30f;
  int cnt = 0;
  for (int i = tid; i < n; i += 256) { const float s = (float)row[i]; v[cnt++] = s; m = fmaxf(m, s); }
  __shared__ float red[4];
#pragma unroll
  for (int off = 32; off > 0; off >>= 1) m = fmaxf(m, __shfl_down(m, off));
  if ((tid & 63) == 0) red[tid >> 6] = m;
  __syncthreads();
  m = fmaxf(fmaxf(red[0], red[1]), fmaxf(red[2], red[3]));
  float sum = 0.f;
  for (int j = 0; j < cnt; ++j) { v[j] = __expf(v[j] - m); sum += v[j]; }
#pragma unroll
  for (int off = 32; off > 0; off >>= 1) sum += __shfl_down(sum, off);
  __syncthreads();
  if ((tid & 63) == 0) red[tid >> 6] = sum;
  __syncthreads();
  sum = red[0] + red[1] + red[2] + red[3];
  const float inv = 1.f / sum;
  cnt = 0;
  for (int i = tid; i < n; i += 256) row[i] = (f16)(v[cnt++] * inv);
  const int kend = ((q >> 7) + 1) << 7;   // pad diagonal tile with zeros (PV reads it)
  for (int i = n + tid; i < kend; i += 256) row[i] = (f16)0.f;
}

// ---------------- PV: Y[q,e] = sum_{k<=q} P[q,k] * Vt[e,k], fp32 out ----------------
__global__ __launch_bounds__(256, 2) void pv_kernel(
    const f16* __restrict__ P, const f16* __restrict__ Vt, float* __restrict__ Y)
{
  __shared__ __align__(16) f16 Ash[BM * BK];
  __shared__ __align__(16) f16 Bsh[BN * BK];
  const int qt = blockIdx.x, et = blockIdx.y, b = blockIdx.z;
  const f16* A  = P  + (size_t)b * SS * SS + (size_t)qt * BM * SS;
  const f16* Bp = Vt + (size_t)b * EE * SS + (size_t)et * BN * SS;
  float* out = Y + (size_t)b * SS * EE;
  Frag fr;
  f32x4 acc[4][4] = {};
  gemm_core(A, Bp, SS, SS, (qt + 1) * (BM / BK), Ash, Bsh, acc, fr);
#pragma unroll
  for (int ni = 0; ni < 4; ++ni) {
    const int c = et * BN + fr.wx * 64 + ni * 16 + fr.l16;
#pragma unroll
    for (int mi = 0; mi < 4; ++mi) {
      const int r = qt * BM + fr.wy * 64 + mi * 16 + fr.quad * 4;
#pragma unroll
      for (int i = 0; i < 4; ++i)
        out[(size_t)(r + i) * EE + c] = acc[mi][ni][i];
    }
  }
}

extern "C" void kernel_launch(void* const* d_in, const int* in_sizes, int n_in,
                              void* d_out, int out_size, void* d_ws, size_t ws_size,
                              hipStream_t stream)
{
  const float* xs  = (const float*)d_in[0];
  const float* WQw = (const float*)d_in[1];
  const float* WQb = (const float*)d_in[2];
  const float* WKw = (const float*)d_in[3];
  const float* WKb = (const float*)d_in[4];
  const float* WVw = (const float*)d_in[5];
  const float* WVb = (const float*)d_in[6];

  const size_t ME = (size_t)BB * SS * EE;   // 8M tokens*dim
  const size_t WE = (size_t)EE * EE;        // 1M weight elems

  f16* Xh = (f16*)d_ws;
  f16* Wq = Xh + ME;
  f16* Wk = Wq + WE;
  f16* Wv = Wk + WE;
  f16* Qh = Wv + WE;
  f16* Kh = Qh + ME;
  f16* Vh = Kh + ME;
  f16* Vt = Vh + ME;
  f16* Sc = Vt + ME;   // BB*SS*SS f16 = 32 MiB

  cast_kernel<<<dim3((unsigned)(ME / 4 / 256)), 256, 0, stream>>>(xs, Xh, (int)(ME / 4));
  cast_kernel<<<dim3((unsigned)(WE / 4 / 256)), 256, 0, stream>>>(WQw, Wq, (int)(WE / 4));
  cast_kernel<<<dim3((unsigned)(WE / 4 / 256)), 256, 0, stream>>>(WKw, Wk, (int)(WE / 4));
  cast_kernel<<<dim3((unsigned)(WE / 4 / 256)), 256, 0, stream>>>(WVw, Wv, (int)(WE / 4));

  qkv_kernel<<<dim3((BB * SS) / BM, EE / BN, 3), 256, 0, stream>>>(
      Xh, Wq, Wk, Wv, WQb, WKb, WVb, Qh, Kh, Vh);
  transpose_kernel<<<dim3(SS / 64, EE / 64, BB), 256, 0, stream>>>(Vh, Vt);
  scores_kernel<<<dim3(SS / BM, SS / BN, BB), 256, 0, stream>>>(Qh, Kh, Sc);
  softmax_kernel<<<dim3(SS, BB), 256, 0, stream>>>(Sc);
  pv_kernel<<<dim3(SS / BM, EE / BN, BB), 256, 0, stream>>>(Sc, Vt, (float*)d_out);
}

// Round 2
// 267.831 us; speedup vs baseline: 1.0736x; 1.0736x over previous
//
#include <hip/hip_runtime.h>
#include <cstdint>
#include <cstddef>

typedef _Float16 f16;
typedef __attribute__((ext_vector_type(4))) _Float16 f16x4;
typedef __attribute__((ext_vector_type(8))) _Float16 f16x8;
typedef __attribute__((ext_vector_type(4))) float f32x4;

static constexpr int BB = 4;
static constexpr int SS = 2048;
static constexpr int EE = 1024;

static constexpr int BM = 128, BN = 128, BK = 32;

// async global->LDS, 16B per lane. LDS dest must be wave-uniform base + lane*16.
__device__ __forceinline__ void gload_lds16(const f16* g, f16* l) {
  __builtin_amdgcn_global_load_lds(
      (const __attribute__((address_space(1))) void*)g,
      (__attribute__((address_space(3))) void*)l, 16, 0, 0);
}

struct Frag {
  int lane, wave, wy, wx, l16, quad;
  __device__ Frag() {
    const int tid = threadIdx.x;
    lane = tid & 63; wave = tid >> 6;
    wy = wave >> 1; wx = wave & 1;
    l16 = lane & 15; quad = lane >> 4;
  }
};

// C[m,n] = sum_k A[m,k] * Bt[n,k]   (both row-major, contraction over fast dim)
// 128x128 tile, 256 threads (4 waves, 2x2 wave grid, 4x4 16x16 MFMA frags/wave)
__device__ __forceinline__ void gemm_core(
    const f16* __restrict__ A, const f16* __restrict__ Bt,
    int lda, int ldb, int kTiles,
    f16* __restrict__ Ash, f16* __restrict__ Bsh,
    f32x4 acc[4][4], const Frag& fr)
{
  // staging: 128x32 f16 tile = 8KB = 512 chunks of 16B; 2 chunks/thread per matrix
  const int ca0 = fr.wave * 128 + fr.lane;   // chunk id in [0,512)
  const int ca1 = ca0 + 64;
  const int ra0 = ca0 >> 2, ka0 = (ca0 & 3) << 3;  // row in tile, col (f16 elems)
  const int ra1 = ca1 >> 2, ka1 = (ca1 & 3) << 3;

  const f16* gA0 = A + (size_t)ra0 * lda + ka0;
  const f16* gA1 = A + (size_t)ra1 * lda + ka1;
  const f16* gB0 = Bt + (size_t)ra0 * ldb + ka0;
  const f16* gB1 = Bt + (size_t)ra1 * ldb + ka1;
  f16* lA0 = Ash + ca0 * 8;   // = wave-uniform base (wave*2048B [+1024B]) + lane*16B
  f16* lA1 = Ash + ca1 * 8;
  f16* lB0 = Bsh + ca0 * 8;
  f16* lB1 = Bsh + ca1 * 8;

  for (int kt = 0; kt < kTiles; ++kt) {
    const int ko = kt * BK;
    gload_lds16(gA0 + ko, lA0);
    gload_lds16(gA1 + ko, lA1);
    gload_lds16(gB0 + ko, lB0);
    gload_lds16(gB1 + ko, lB1);
    __syncthreads();   // drains vmcnt(0) before barrier -> LDS tiles ready
    f16x8 af[4], bf[4];
#pragma unroll
    for (int mi = 0; mi < 4; ++mi)
      af[mi] = *(const f16x8*)(Ash + (fr.wy * 64 + mi * 16 + fr.l16) * BK + fr.quad * 8);
#pragma unroll
    for (int ni = 0; ni < 4; ++ni)
      bf[ni] = *(const f16x8*)(Bsh + (fr.wx * 64 + ni * 16 + fr.l16) * BK + fr.quad * 8);
#pragma unroll
    for (int mi = 0; mi < 4; ++mi)
#pragma unroll
      for (int ni = 0; ni < 4; ++ni)
        acc[mi][ni] = __builtin_amdgcn_mfma_f32_16x16x32_f16(af[mi], bf[ni], acc[mi][ni], 0, 0, 0);
    __syncthreads();
  }
}

// ---------------- cast fp32 -> f16 ----------------
__global__ __launch_bounds__(256) void cast_kernel(
    const float* __restrict__ in, f16* __restrict__ out, int n4)
{
  const int i = blockIdx.x * 256 + threadIdx.x;
  if (i < n4) {
    const float4 f = ((const float4*)in)[i];
    f16x4 h;
    h.x = (f16)f.x; h.y = (f16)f.y; h.z = (f16)f.z; h.w = (f16)f.w;
    ((f16x4*)out)[i] = h;
  }
}

// cast the three weight matrices in one launch (z picks the matrix)
__global__ __launch_bounds__(256) void cast_w_kernel(
    const float* __restrict__ w0, const float* __restrict__ w1, const float* __restrict__ w2,
    f16* __restrict__ o0, f16* __restrict__ o1, f16* __restrict__ o2, int n4)
{
  const int z = blockIdx.y;
  const float* in = (z == 0) ? w0 : (z == 1) ? w1 : w2;
  f16* out = (z == 0) ? o0 : (z == 1) ? o1 : o2;
  const int i = blockIdx.x * 256 + threadIdx.x;
  if (i < n4) {
    const float4 f = ((const float4*)in)[i];
    f16x4 h;
    h.x = (f16)f.x; h.y = (f16)f.y; h.z = (f16)f.z; h.w = (f16)f.w;
    ((f16x4*)out)[i] = h;
  }
}

// ---------------- QKV projection: C = X @ W^T + b ----------------
__global__ __launch_bounds__(256, 4) void qkv_kernel(
    const f16* __restrict__ X,
    const f16* __restrict__ W0, const f16* __restrict__ W1, const f16* __restrict__ W2,
    const float* __restrict__ b0, const float* __restrict__ b1, const float* __restrict__ b2,
    f16* __restrict__ O0, f16* __restrict__ O1, f16* __restrict__ O2)
{
  __shared__ __align__(16) f16 Ash[BM * BK];
  __shared__ __align__(16) f16 Bsh[BN * BK];
  const int z = blockIdx.z;
  const f16* W = (z == 0) ? W0 : (z == 1) ? W1 : W2;
  const float* bias = (z == 0) ? b0 : (z == 1) ? b1 : b2;
  f16* out = (z == 0) ? O0 : (z == 1) ? O1 : O2;
  const int row0 = blockIdx.x * BM, col0 = blockIdx.y * BN;
  Frag fr;
  f32x4 acc[4][4] = {};
  gemm_core(X + (size_t)row0 * EE, W + (size_t)col0 * EE, EE, EE, EE / BK, Ash, Bsh, acc, fr);
#pragma unroll
  for (int ni = 0; ni < 4; ++ni) {
    const int c = col0 + fr.wx * 64 + ni * 16 + fr.l16;
    const float bv = bias[c];
#pragma unroll
    for (int mi = 0; mi < 4; ++mi) {
      const int r = row0 + fr.wy * 64 + mi * 16 + fr.quad * 4;
#pragma unroll
      for (int i = 0; i < 4; ++i)
        out[(size_t)(r + i) * EE + c] = (f16)(acc[mi][ni][i] + bv);
    }
  }
}

// ---------------- V transpose: Vt[e][s] = V[s][e] (per batch) ----------------
__global__ __launch_bounds__(256) void transpose_kernel(
    const f16* __restrict__ V, f16* __restrict__ Vt)
{
  __shared__ __align__(16) f16 t[64][68];
  const int b = blockIdx.z;
  const int s0 = blockIdx.x * 64, e0 = blockIdx.y * 64;
  const int tid = threadIdx.x;
  const int r = tid >> 4;
  const int c4 = (tid & 15) << 2;
  const f16* src = V + (size_t)b * SS * EE;
  f16* dst = Vt + (size_t)b * EE * SS;
#pragma unroll
  for (int i = 0; i < 4; ++i) {
    const int row = i * 16 + r;
    const f16x4 v = *(const f16x4*)(src + (size_t)(s0 + row) * EE + e0 + c4);
    *(f16x4*)&t[row][c4] = v;
  }
  __syncthreads();
#pragma unroll
  for (int i = 0; i < 4; ++i) {
    const int row = i * 16 + r;   // e-local
    f16x4 v;
    v.x = t[c4 + 0][row]; v.y = t[c4 + 1][row];
    v.z = t[c4 + 2][row]; v.w = t[c4 + 3][row];
    *(f16x4*)(dst + (size_t)(e0 + row) * SS + s0 + c4) = v;
  }
}

// ---------------- scores: Sc[q,k] = (Q[q,:] . K[k,:]) / 32, lower-tri tiles only ----------------
// grid.x enumerates the 136 lower-triangular tiles directly (no early-exit blocks)
__global__ __launch_bounds__(256, 4) void scores_kernel(
    const f16* __restrict__ Q, const f16* __restrict__ Kh, f16* __restrict__ Sc)
{
  __shared__ __align__(16) f16 Ash[BM * BK];
  __shared__ __align__(16) f16 Bsh[BN * BK];
  const int t = blockIdx.x, b = blockIdx.z;
  int qt = 0;
  while ((qt + 1) * (qt + 2) / 2 <= t) ++qt;     // <=16 scalar iterations
  const int kt = t - qt * (qt + 1) / 2;
  const f16* A  = Q  + (size_t)b * SS * EE + (size_t)qt * BM * EE;
  const f16* Bp = Kh + (size_t)b * SS * EE + (size_t)kt * BN * EE;
  f16* out = Sc + (size_t)b * SS * SS;
  Frag fr;
  f32x4 acc[4][4] = {};
  gemm_core(A, Bp, EE, EE, EE / BK, Ash, Bsh, acc, fr);
  const float scale = 0.03125f;   // 1/sqrt(1024)
#pragma unroll
  for (int ni = 0; ni < 4; ++ni) {
    const int c = kt * BN + fr.wx * 64 + ni * 16 + fr.l16;
#pragma unroll
    for (int mi = 0; mi < 4; ++mi) {
      const int r = qt * BM + fr.wy * 64 + mi * 16 + fr.quad * 4;
#pragma unroll
      for (int i = 0; i < 4; ++i)
        out[(size_t)(r + i) * SS + c] = (f16)(acc[mi][ni][i] * scale);
    }
  }
}

// ---------------- in-place causal softmax over row q (vectorized f16x8) ----------------
// 256 threads x 8 f16 = 2048 = full row span; zero-fills (n, kend) so PV reads clean tiles
__global__ __launch_bounds__(256) void softmax_kernel(f16* __restrict__ Sc)
{
  const int q = blockIdx.x, b = blockIdx.y;
  f16* row = Sc + (size_t)b * SS * SS + (size_t)q * SS;
  const int n = q + 1;
  const int kend = ((q >> 7) + 1) << 7;   // diagonal-tile edge
  const int tid = threadIdx.x;
  const int i0 = tid * 8;

  float v[8];
  if (i0 + 8 <= n) {
    const f16x8 h = *(const f16x8*)(row + i0);
#pragma unroll
    for (int j = 0; j < 8; ++j) v[j] = (float)h[j];
  } else {
#pragma unroll
    for (int j = 0; j < 8; ++j) {
      const int idx = i0 + j;
      v[j] = (idx < n) ? (float)row[idx] : -1e30f;
    }
  }

  float m = v[0];
#pragma unroll
  for (int j = 1; j < 8; ++j) m = fmaxf(m, v[j]);
  __shared__ float red[4];
#pragma unroll
  for (int off = 32; off > 0; off >>= 1) m = fmaxf(m, __shfl_down(m, off));
  if ((tid & 63) == 0) red[tid >> 6] = m;
  __syncthreads();
  m = fmaxf(fmaxf(red[0], red[1]), fmaxf(red[2], red[3]));

  float sum = 0.f;
#pragma unroll
  for (int j = 0; j < 8; ++j) {
    v[j] = (i0 + j < n) ? __expf(v[j] - m) : 0.f;
    sum += v[j];
  }
#pragma unroll
  for (int off = 32; off > 0; off >>= 1) sum += __shfl_down(sum, off);
  __syncthreads();
  if ((tid & 63) == 0) red[tid >> 6] = sum;
  __syncthreads();
  sum = red[0] + red[1] + red[2] + red[3];
  const float inv = 1.f / sum;

  if (i0 < kend) {                         // kend is a multiple of 128 >= n
    f16x8 h;
#pragma unroll
    for (int j = 0; j < 8; ++j) h[j] = (f16)(v[j] * inv);   // v==0 beyond n
    *(f16x8*)(row + i0) = h;
  }
}

// ---------------- PV: Y[q,e] = sum_{k<=q} P[q,k] * Vt[e,k], fp32 out ----------------
// qt reversed so the heaviest (diagonal-adjacent) blocks dispatch first
__global__ __launch_bounds__(256, 4) void pv_kernel(
    const f16* __restrict__ P, const f16* __restrict__ Vt, float* __restrict__ Y)
{
  __shared__ __align__(16) f16 Ash[BM * BK];
  __shared__ __align__(16) f16 Bsh[BN * BK];
  const int qt = (gridDim.x - 1) - blockIdx.x, et = blockIdx.y, b = blockIdx.z;
  const f16* A  = P  + (size_t)b * SS * SS + (size_t)qt * BM * SS;
  const f16* Bp = Vt + (size_t)b * EE * SS + (size_t)et * BN * SS;
  float* out = Y + (size_t)b * SS * EE;
  Frag fr;
  f32x4 acc[4][4] = {};
  gemm_core(A, Bp, SS, SS, (qt + 1) * (BM / BK), Ash, Bsh, acc, fr);
#pragma unroll
  for (int ni = 0; ni < 4; ++ni) {
    const int c = et * BN + fr.wx * 64 + ni * 16 + fr.l16;
#pragma unroll
    for (int mi = 0; mi < 4; ++mi) {
      const int r = qt * BM + fr.wy * 64 + mi * 16 + fr.quad * 4;
#pragma unroll
      for (int i = 0; i < 4; ++i)
        out[(size_t)(r + i) * EE + c] = acc[mi][ni][i];
    }
  }
}

extern "C" void kernel_launch(void* const* d_in, const int* in_sizes, int n_in,
                              void* d_out, int out_size, void* d_ws, size_t ws_size,
                              hipStream_t stream)
{
  const float* xs  = (const float*)d_in[0];
  const float* WQw = (const float*)d_in[1];
  const float* WQb = (const float*)d_in[2];
  const float* WKw = (const float*)d_in[3];
  const float* WKb = (const float*)d_in[4];
  const float* WVw = (const float*)d_in[5];
  const float* WVb = (const float*)d_in[6];

  const size_t ME = (size_t)BB * SS * EE;   // 8M tokens*dim
  const size_t WE = (size_t)EE * EE;        // 1M weight elems

  f16* Xh = (f16*)d_ws;
  f16* Wq = Xh + ME;
  f16* Wk = Wq + WE;
  f16* Wv = Wk + WE;
  f16* Qh = Wv + WE;
  f16* Kh = Qh + ME;
  f16* Vh = Kh + ME;
  f16* Vt = Vh + ME;
  f16* Sc = Vt + ME;   // BB*SS*SS f16 = 32 MiB

  cast_kernel<<<dim3((unsigned)(ME / 4 / 256)), 256, 0, stream>>>(xs, Xh, (int)(ME / 4));
  cast_w_kernel<<<dim3((unsigned)(WE / 4 / 256), 3), 256, 0, stream>>>(
      WQw, WKw, WVw, Wq, Wk, Wv, (int)(WE / 4));

  qkv_kernel<<<dim3((BB * SS) / BM, EE / BN, 3), 256, 0, stream>>>(
      Xh, Wq, Wk, Wv, WQb, WKb, WVb, Qh, Kh, Vh);
  transpose_kernel<<<dim3(SS / 64, EE / 64, BB), 256, 0, stream>>>(Vh, Vt);
  const int nTri = (SS / BM) * (SS / BM + 1) / 2;   // 136
  scores_kernel<<<dim3(nTri, 1, BB), 256, 0, stream>>>(Qh, Kh, Sc);
  softmax_kernel<<<dim3(SS, BB), 256, 0, stream>>>(Sc);
  pv_kernel<<<dim3(SS / BM, EE / BN, BB), 256, 0, stream>>>(Sc, Vt, (float*)d_out);
}